// Round 15
// baseline (5723.935 us; speedup 1.0000x reference)
//
#include <hip/hip_runtime.h>
#include <hip/hip_bf16.h>

// Round 27: houtg v2 — gather/LDS-write vectorization. r26: 515.8 (launch
// model confirmed: -17us for -4 dispatches). houtg now top at 73us:
// BANK_CONFLICT 3.1M (As[sch][spx+j] scalar writes = 8-way), 32 scalar
// scattered cb32 gathers per slice, VALU 31%, Mfma 0 -> latency-dead.
// Fix: the 8 elements a z-slice needs (e = kz*8..+7) are CONTIGUOUS in
// cb32 -> per quad-chunk each thread loads 4 codes x one float4 (8 b128
// gathers/slice vs 32 scalars); As row-segment assembled in regs, written
// as ONE b128 (lanes 0-7 cover all 32 banks -> conflict-free); IdxS LDS +
// its barrier deleted (idx kept in 4 regs, same-thread produce/consume).
// K-chunk order unchanged -> per-block FMA accumulation bit-identical.
// All other kernels byte-identical to r26 (passed, 515.8).
// Outputs (f32): out[1048576] | loss[1] | zq_p[4194304].

typedef float f32x4  __attribute__((ext_vector_type(4)));
typedef short bf16x8 __attribute__((ext_vector_type(8)));

__device__ __forceinline__ float silu_rw(float x){ return x / (1.f + expf(-x)); }
__device__ __forceinline__ float b2f_rw(__hip_bfloat16 v){ return __bfloat162float(v); }
__device__ __forceinline__ float ldv_rw(const void* p, int i, int f32m){
  if (f32m) return ((const float*)p)[i];
  return b2f_rw(((const __hip_bfloat16*)p)[i]);
}
__device__ __forceinline__ unsigned short f2bf_rw(float x){   // f32 -> bf16 RNE
  unsigned u = __float_as_uint(x);
  unsigned r = ((u >> 16) & 1u) + 0x7FFFu;
  return (unsigned short)((u + r) >> 16);
}
__device__ __forceinline__ float bf2f_rw(unsigned short h){
  return __uint_as_float(((unsigned)h) << 16);
}

// ---------------- workspace layout (float offsets) ----------------
#define FLAGS_OFF 0
#define LOSS_OFF  4
#define STATS_OFF 8
#define CNT_OFF   72         // 8 ints: fallback counters per chunk
#define CMAX_OFF  80         // cmaxp[0..3]: per-cbprep-block max |c|
#define CB32_OFF  128        // 1024x32 f32
#define CBN_OFF   32896      // 1024
#define IDXP_OFF  33984      // 131072 int
#define IDXN_OFF  165056     // 131072 int
#define CBHL_OFF  296192     // interleaved hi/lo bf16 table (32768 f32 slots)
#define LIST_OFF  328960     // 131072 int (uncertain list, reused per chunk)
#define R2_OFF    460032     // lnp -> hcat_p accum (524288)
#define R3_OFF    984320     // lnn -> hcat_n accum (524288)
#define R1_OFF    1508608    // h (1048576) / z chunks (CS*262144)

// ------ cbprep v3: fused dtype-detect + codebook prep + accumulator init ---
__global__ __launch_bounds__(256) void cbprep_rw(const void* cbv,
    float* cb32, float* cbn, short* cbhl, float* wsb){
  __shared__ int bad_s;
  __shared__ float mx[256];
  const int tid = threadIdx.x;
  if (tid == 0) bad_s = 0;
  __syncthreads();
  const unsigned short* u = (const unsigned short*)cbv;
  int local = 0;
  for (int i = tid; i < 32768; i += 256){
    unsigned e = (u[i] >> 7) & 0xFF;
    if (e >= 126) local = 1;
  }
  if (local) bad_s = 1;
  __syncthreads();
  const int f32m = bad_s;

  const int j = blockIdx.x * 256 + tid;          // grid 4 -> j in [0,1024)
  float s = 0.f;
  const int tb = ((j >> 4) << 10) + ((j & 15) << 5);
  for (int e = 0; e < 32; ++e){
    float v = ldv_rw(cbv, j*32 + e, f32m);
    cb32[j*32 + e] = v;
    unsigned short h = f2bf_rw(v);
    cbhl[tb + e]       = (short)h;
    cbhl[tb + e + 512] = (short)f2bf_rw(v - bf2f_rw(h));
    s += v*v;
  }
  cbn[j] = s;
  mx[tid] = sqrtf(s);
  __syncthreads();
  for (int st = 128; st > 0; st >>= 1){
    if (tid < st) mx[tid] = fmaxf(mx[tid], mx[tid + st]);
    __syncthreads();
  }
  if (tid == 0){
    wsb[CMAX_OFF + blockIdx.x] = mx[0];
    wsb[FLAGS_OFF] = f32m ? 1.f : 0.f;           // idempotent across blocks
    if (blockIdx.x == 0){
      wsb[LOSS_OFF] = 0.f; wsb[LOSS_OFF + 1] = 0.f;
      int* c = (int*)(wsb + CNT_OFF);
      #pragma unroll
      for (int k = 0; k < 8; ++k) c[k] = 0;
    }
  }
}

// ---------------- gemm2 (r11, verified): 32px x 64out tiles ----------------
// Instantiated here only for INMODE 0 (z-gemm) and 2 (conv_in).
template<int KCH, int INMODE, bool OUTSILU, bool ATOMIC, int LEVELS>
__global__ __launch_bounds__(256) void gemm2_rw(
    const float* __restrict__ inF, const float* __restrict__ inF2,
    const void* __restrict__ inV,
    const void* __restrict__ W, const void* __restrict__ biasO,
    const void* __restrict__ sbA, const void* __restrict__ sbB,
    const int* __restrict__ idxin, const float* __restrict__ cb32,
    float* __restrict__ outF, const float* __restrict__ flags,
    int KDIM, int OUTC, int o_off, int b_base, int ib_sub, int ob_sub)
{
  __shared__ float As[32][32];
  __shared__ float Bs[32][68];

  const int f32m = (flags[0] != 0.f);
  const int t  = threadIdx.x;
  const int q0 = (blockIdx.x << 5) + (b_base << 8);
  const int b  = q0 >> 8;
  const int p0 = q0 & 255;
  const int o0 = blockIdx.y << 6;
  const int k0base = blockIdx.z * KCH;
  const int tx = t & 15, ty = t >> 4;
  float acc[4][2] = {};

  const int sch = t >> 3, spx = (t & 7) << 2;

  for (int kc = 0; kc < KCH; kc += 32){
    const int k0 = k0base + kc;
    if constexpr (INMODE == 0){
      const float4 v = *reinterpret_cast<const float4*>(
          &inF[(((b - ib_sub)*KDIM + k0 + sch) << 8) + p0 + spx]);
      *reinterpret_cast<float4*>(&As[sch][spx]) = v;
    } else { // INMODE 2
      if (f32m){
        const float* xf = (const float*)inV;
        float4 v = *reinterpret_cast<const float4*>(&xf[((b*KDIM + k0 + sch) << 8) + p0 + spx]);
        v.x = silu_rw(v.x); v.y = silu_rw(v.y); v.z = silu_rw(v.z); v.w = silu_rw(v.w);
        *reinterpret_cast<float4*>(&As[sch][spx]) = v;
      } else {
        const __hip_bfloat16* xb = (const __hip_bfloat16*)inV;
        const int off = ((b*KDIM + k0 + sch) << 8) + p0 + spx;
        #pragma unroll
        for (int j = 0; j < 4; ++j) As[sch][spx + j] = silu_rw(b2f_rw(xb[off + j]));
      }
    }
    if (f32m){
      const float* Wf = (const float*)W;
      #pragma unroll
      for (int r = 0; r < 8; ++r){
        int ii = t + (r << 8); int oo = ii >> 5, cc = ii & 31;
        Bs[cc][oo] = Wf[(o0 + oo)*KDIM + k0 + cc];
      }
    } else {
      const __hip_bfloat16* Wb = (const __hip_bfloat16*)W;
      #pragma unroll
      for (int r = 0; r < 8; ++r){
        int ii = t + (r << 8); int oo = ii >> 5, cc = ii & 31;
        Bs[cc][oo] = b2f_rw(Wb[(o0 + oo)*KDIM + k0 + cc]);
      }
    }
    __syncthreads();
    #pragma unroll
    for (int kk = 0; kk < 32; ++kk){
      const float2 a = *reinterpret_cast<const float2*>(&As[kk][tx << 1]);
      const float4 w = *reinterpret_cast<const float4*>(&Bs[kk][ty << 2]);
      acc[0][0] += w.x*a.x; acc[0][1] += w.x*a.y;
      acc[1][0] += w.y*a.x; acc[1][1] += w.y*a.y;
      acc[2][0] += w.z*a.x; acc[2][1] += w.z*a.y;
      acc[3][0] += w.w*a.x; acc[3][1] += w.w*a.y;
    }
    __syncthreads();
  }
  #pragma unroll
  for (int i = 0; i < 4; ++i){
    const int o = o0 + (ty << 2) + i;
    const int base = (((b - ob_sub)*OUTC + o_off + o) << 8) + p0 + (tx << 1);
    const float bb = ldv_rw(biasO, o, f32m);
    float v0 = acc[i][0] + bb, v1 = acc[i][1] + bb;
    if constexpr (OUTSILU){ v0 = silu_rw(v0); v1 = silu_rw(v1); }
    *reinterpret_cast<float2*>(&outF[base]) = make_float2(v0, v1);
  }
}

// ------- houtg v2: merged hout_p + hout_n, vectorized gather/As-write ------
// Grid (128, 2, 8): z>>2 selects group (0=p LEVELS4, 1=n LEVELS1), z&3 = kz
// split-K slice (K 256, e = kz*8..kz*8+7). Per quad-chunk each thread loads
// its 4 codes' 4 consecutive elements as one float4 (cb32 row-contiguous);
// As written as one b128 per chunk (conflict-free); idx in regs (no IdxS).
// K-chunk order and per-output FMA order identical to r26.
__global__ __launch_bounds__(256) void houtg_rw(
    const int* __restrict__ idxp, const int* __restrict__ idxn,
    const void* __restrict__ Wp, const void* __restrict__ Wn,
    const float* __restrict__ cb32, float* __restrict__ R2,
    float* __restrict__ R3, const float* __restrict__ flags)
{
  __shared__ float As[32][32];
  __shared__ float Bs[32][68];

  const int f32m = (flags[0] != 0.f);
  const int grp = blockIdx.z >> 2;
  const int* __restrict__ idxin = grp ? idxn : idxp;
  const void* __restrict__ W    = grp ? Wn : Wp;
  float* __restrict__ outF      = grp ? R3 : R2;

  const int t  = threadIdx.x;
  const int q0 = blockIdx.x << 5;
  const int b  = q0 >> 8;
  const int p0 = q0 & 255;
  const int o0 = blockIdx.y << 6;
  const int kz = blockIdx.z & 3;
  const int tx = t & 15, ty = t >> 4;
  float acc[4][2] = {};

  const int sch = t >> 3, spx = (t & 7) << 2;

  // this thread's 4 code indices (produced and consumed by the same thread)
  int idxr[4];
  #pragma unroll
  for (int j = 0; j < 4; ++j){
    const int p = p0 + spx + j;
    if (grp == 0){                      // LEVELS 4 (phylo)
      const int l = sch >> 3, kp = sch & 7;
      idxr[j] = idxin[b*8192 + (((kp << 8) + p) << 2) + l] & 1023;
    } else {                            // LEVELS 1
      idxr[j] = idxin[b*8192 + (sch << 8) + p] & 1023;
    }
  }

  const float4* cb4 = reinterpret_cast<const float4*>(cb32);

  #pragma unroll
  for (int qc = 0; qc < 2; ++qc){
    // gather: 4 codes x 4 consecutive elements (e0 = kz*8 + qc*4) as float4
    float ga[4][4];
    #pragma unroll
    for (int j = 0; j < 4; ++j){
      const float4 g = cb4[(idxr[j] << 3) + (kz << 1) + qc];
      ga[j][0] = g.x; ga[j][1] = g.y; ga[j][2] = g.z; ga[j][3] = g.w;
    }
    #pragma unroll
    for (int cc = 0; cc < 4; ++cc){
      const int k0 = (kz << 8) + (qc << 7) + (cc << 5);
      // As: one conflict-free b128 per thread
      *reinterpret_cast<float4*>(&As[sch][spx]) =
          make_float4(ga[0][cc], ga[1][cc], ga[2][cc], ga[3][cc]);
      if (f32m){
        const float* Wf = (const float*)W;
        #pragma unroll
        for (int r = 0; r < 8; ++r){
          int ii = t + (r << 8); int oo = ii >> 5, cc2 = ii & 31;
          Bs[cc2][oo] = Wf[(o0 + oo)*1024 + k0 + cc2];
        }
      } else {
        const __hip_bfloat16* Wb = (const __hip_bfloat16*)W;
        #pragma unroll
        for (int r = 0; r < 8; ++r){
          int ii = t + (r << 8); int oo = ii >> 5, cc2 = ii & 31;
          Bs[cc2][oo] = b2f_rw(Wb[(o0 + oo)*1024 + k0 + cc2]);
        }
      }
      __syncthreads();
      #pragma unroll
      for (int kk = 0; kk < 32; ++kk){
        const float2 a = *reinterpret_cast<const float2*>(&As[kk][tx << 1]);
        const float4 w = *reinterpret_cast<const float4*>(&Bs[kk][ty << 2]);
        acc[0][0] += w.x*a.x; acc[0][1] += w.x*a.y;
        acc[1][0] += w.y*a.x; acc[1][1] += w.y*a.y;
        acc[2][0] += w.z*a.x; acc[2][1] += w.z*a.y;
        acc[3][0] += w.w*a.x; acc[3][1] += w.w*a.y;
      }
      __syncthreads();
    }
  }
  #pragma unroll
  for (int i = 0; i < 4; ++i){
    const int o = o0 + (ty << 2) + i;
    const int base = ((b*128 + o) << 8) + p0 + (tx << 1);
    atomicAdd(&outF[base + 0], acc[i][0]);
    atomicAdd(&outF[base + 1], acc[i][1]);
  }
}

// ------- coutf: conv_out (r18 INMODE5 semantics) + fused loss finalize -----
__global__ __launch_bounds__(256) void coutf_rw(
    const float* __restrict__ inF, const float* __restrict__ inF2,
    const void* __restrict__ W, const void* __restrict__ biasO,
    const void* __restrict__ sbA, const void* __restrict__ sbB,
    float* __restrict__ outF, const float* __restrict__ flags,
    const float* __restrict__ lossacc, float* __restrict__ outL)
{
  __shared__ float As[32][32];
  __shared__ float Bs[32][68];

  const int f32m = (flags[0] != 0.f);
  const int t  = threadIdx.x;
  const int q0 = blockIdx.x << 5;
  const int b  = q0 >> 8;
  const int p0 = q0 & 255;
  const int o0 = blockIdx.y << 6;
  const int tx = t & 15, ty = t >> 4;
  float acc[4][2] = {};

  const int sch = t >> 3, spx = (t & 7) << 2;

  if (blockIdx.x == 0 && blockIdx.y == 0 && t == 0)
    outL[0] = 1.25f * (lossacc[0] + lossacc[1]) * (1.f/4194304.f);

  for (int kc = 0; kc < 256; kc += 32){
    const int k0 = kc;
    const float* src = (k0 < 128) ? inF : inF2;
    const void* sb   = (k0 < 128) ? sbA : sbB;
    const int kh = k0 & 127;
    const float bb = ldv_rw(sb, kh + sch, f32m);
    float4 v = *reinterpret_cast<const float4*>(&src[((b*128 + kh + sch) << 8) + p0 + spx]);
    v.x = silu_rw(v.x + bb); v.y = silu_rw(v.y + bb);
    v.z = silu_rw(v.z + bb); v.w = silu_rw(v.w + bb);
    *reinterpret_cast<float4*>(&As[sch][spx]) = v;
    if (f32m){
      const float* Wf = (const float*)W;
      #pragma unroll
      for (int r = 0; r < 8; ++r){
        int ii = t + (r << 8); int oo = ii >> 5, cc = ii & 31;
        Bs[cc][oo] = Wf[(o0 + oo)*256 + k0 + cc];
      }
    } else {
      const __hip_bfloat16* Wb = (const __hip_bfloat16*)W;
      #pragma unroll
      for (int r = 0; r < 8; ++r){
        int ii = t + (r << 8); int oo = ii >> 5, cc = ii & 31;
        Bs[cc][oo] = b2f_rw(Wb[(o0 + oo)*256 + k0 + cc]);
      }
    }
    __syncthreads();
    #pragma unroll
    for (int kk = 0; kk < 32; ++kk){
      const float2 a = *reinterpret_cast<const float2*>(&As[kk][tx << 1]);
      const float4 w = *reinterpret_cast<const float4*>(&Bs[kk][ty << 2]);
      acc[0][0] += w.x*a.x; acc[0][1] += w.x*a.y;
      acc[1][0] += w.y*a.x; acc[1][1] += w.y*a.y;
      acc[2][0] += w.z*a.x; acc[2][1] += w.z*a.y;
      acc[3][0] += w.w*a.x; acc[3][1] += w.w*a.y;
    }
    __syncthreads();
  }
  #pragma unroll
  for (int i = 0; i < 4; ++i){
    const int o = o0 + (ty << 2) + i;
    const int base = ((b*256 + o) << 8) + p0 + (tx << 1);
    const float bb = ldv_rw(biasO, o, f32m);
    *reinterpret_cast<float2*>(&outF[base]) =
        make_float2(acc[i][0] + bb, acc[i][1] + bb);
  }
}

// ---------------- per-sample LN stats over silu(h_half) ----------------
__global__ __launch_bounds__(256) void stats_rw(const float* __restrict__ h, float* __restrict__ stats){
  const int b = blockIdx.x >> 1, half = blockIdx.x & 1;
  const float* base = h + ((b*256 + half*128) << 8);
  float s = 0.f, s2 = 0.f;
  for (int i = threadIdx.x; i < 32768; i += 256){
    float a = silu_rw(base[i]);
    s += a; s2 += a*a;
  }
  __shared__ float sh[2][256];
  sh[0][threadIdx.x] = s; sh[1][threadIdx.x] = s2;
  __syncthreads();
  for (int st = 128; st > 0; st >>= 1){
    if (threadIdx.x < st){
      sh[0][threadIdx.x] += sh[0][threadIdx.x + st];
      sh[1][threadIdx.x] += sh[1][threadIdx.x + st];
    }
    __syncthreads();
  }
  if (threadIdx.x == 0){
    float mu  = sh[0][0] * (1.f/32768.f);
    float var = sh[1][0] * (1.f/32768.f) - mu*mu;
    stats[half*32 + b]      = mu;
    stats[half*32 + 16 + b] = 1.f / sqrtf(var + 1e-5f);
  }
}

// ---------------- LN apply ----------------
__global__ __launch_bounds__(256) void ln_rw(const float* __restrict__ h,
    const void* lwp, const void* lbp, const void* lwn, const void* lbn,
    const float* __restrict__ stats, const float* __restrict__ flags,
    float* __restrict__ lnp, float* __restrict__ lnn){
  const int f32m = (flags[0] != 0.f);
  int i = blockIdx.x * 256 + threadIdx.x;
  int b = i >> 16, c = (i >> 8) & 255, p = i & 255;
  float a = silu_rw(h[i]);
  if (c < 128){
    float v = (a - stats[b]) * stats[16 + b] * ldv_rw(lwp, (c << 8) + p, f32m) + ldv_rw(lbp, (c << 8) + p, f32m);
    lnp[((b*128 + c) << 8) + p] = v;
  } else {
    int cc = c - 128;
    float v = (a - stats[32 + b]) * stats[48 + b] * ldv_rw(lwn, (cc << 8) + p, f32m) + ldv_rw(lbn, (cc << 8) + p, f32m);
    lnn[((b*128 + cc) << 8) + p] = v;
  }
}

// ---------------- VQ search v6b (r18-exact; cmax = max of 4 partials) ------
template<int LEVELS>
__global__ __launch_bounds__(512, 4) void quantm_rw(
    const float* __restrict__ z, const short* __restrict__ cbhl,
    const float* __restrict__ cbn, const float* __restrict__ cmaxp,
    int* __restrict__ idxout, float* __restrict__ lossacc,
    int* __restrict__ cnt, int* __restrict__ list, int b_base)
{
  __shared__ float mgm1[4][4][8], mgm2[4][4][8];
  __shared__ int   mgj [4][4][8];
  __shared__ float red[4];

  const int tid  = threadIdx.x;
  const int lane = tid & 63, wid = tid >> 6;
  const int lc = lane & 15, gq = lane >> 4;
  const int pg = wid & 3, ch = wid >> 2;    // pixel group, code half
  const int bid  = blockIdx.x;
  const int bl   = bid >> 6;                // local batch
  const int rest = bid & 63;
  const int g = rest >> 1, half = rest & 1;
  int cb, wbase, wstep;
  if (LEVELS == 4){ cb = (g & 3)*8 + (g >> 2); wbase = (g >> 2)*1024 + (g & 3); wstep = 4; }
  else            { cb = g;                    wbase = g << 8;                  wstep = 1; }
  const int pb = half*128 + pg*32;

  // ---- load z rows, build -2z hi/lo bf16 A-fragments, partial |z|^2 ----
  bf16x8 ah0, al0, ah1, al1;
  float zn0 = 0.f, zn1 = 0.f;
  const int zoff = (((bl << 10) + cb) << 8) + pb + lc;
  const int e0 = gq << 3;
  #pragma unroll
  for (int i = 0; i < 8; ++i){
    const int zo = zoff + ((e0 + i) << 13);
    const float z0 = z[zo];
    const float z1 = z[zo + 16];
    zn0 += z0*z0; zn1 += z1*z1;
    const float s0 = -2.f*z0, s1 = -2.f*z1;
    const unsigned short h0 = f2bf_rw(s0);
    const unsigned short h1 = f2bf_rw(s1);
    ah0[i] = (short)h0; al0[i] = (short)f2bf_rw(s0 - bf2f_rw(h0));
    ah1[i] = (short)h1; al1[i] = (short)f2bf_rw(s1 - bf2f_rw(h1));
  }
  zn0 += __shfl_xor(zn0, 16); zn0 += __shfl_xor(zn0, 32);   // full zn for row lc
  zn1 += __shfl_xor(zn1, 16); zn1 += __shfl_xor(zn1, 32);

  float m1[8], m2[8]; int j1[8];
  #pragma unroll
  for (int s = 0; s < 8; ++s){ m1[s] = __builtin_inff(); m2[s] = __builtin_inff(); j1[s] = 0; }

  // interleaved table: wave's tiles T = ch*32 + t; shorts base:
  const short* bp  = cbhl + (ch << 15) + (lc << 5) + (gq << 3);
  const float* cnp = cbn + (ch << 9) + lc;

  bf16x8 bh  = *reinterpret_cast<const bf16x8*>(bp);
  bf16x8 blo = *reinterpret_cast<const bf16x8*>(bp + 512);
  float  cnv = cnp[0];

  #pragma unroll 2
  for (int t = 0; t < 32; ++t){
    const int tn = (t < 31) ? t + 1 : 31;      // clamped prefetch index
    const bf16x8 bhn  = *reinterpret_cast<const bf16x8*>(bp + (tn << 10));
    const bf16x8 blon = *reinterpret_cast<const bf16x8*>(bp + (tn << 10) + 512);
    const float  cnn  = cnp[tn << 4];

    f32x4 a0 = {cnv, cnv, cnv, cnv};
    f32x4 a1 = {cnv, cnv, cnv, cnv};
    a0 = __builtin_amdgcn_mfma_f32_16x16x32_bf16(ah0, bh,  a0, 0, 0, 0);
    a0 = __builtin_amdgcn_mfma_f32_16x16x32_bf16(ah0, blo, a0, 0, 0, 0);
    a0 = __builtin_amdgcn_mfma_f32_16x16x32_bf16(al0, bh,  a0, 0, 0, 0);
    a1 = __builtin_amdgcn_mfma_f32_16x16x32_bf16(ah1, bh,  a1, 0, 0, 0);
    a1 = __builtin_amdgcn_mfma_f32_16x16x32_bf16(ah1, blo, a1, 0, 0, 0);
    a1 = __builtin_amdgcn_mfma_f32_16x16x32_bf16(al1, bh,  a1, 0, 0, 0);

    const int jc = (((ch << 5) + t) << 4) + lc;
    #pragma unroll
    for (int r = 0; r < 4; ++r){
      const float d0 = a0[r];
      m2[r] = __builtin_amdgcn_fmed3f(d0, m1[r], m2[r]);
      const bool t0 = d0 < m1[r];
      j1[r] = t0 ? jc : j1[r]; m1[r] = t0 ? d0 : m1[r];
      const float d1 = a1[r];
      m2[4+r] = __builtin_amdgcn_fmed3f(d1, m1[4+r], m2[4+r]);
      const bool t1 = d1 < m1[4+r];
      j1[4+r] = t1 ? jc : j1[4+r]; m1[4+r] = t1 ? d1 : m1[4+r];
    }
    bh = bhn; blo = blon; cnv = cnn;
  }

  // ---- 16-lane top-2 merge (cols of each row live in one 16-lane group) ----
  #pragma unroll
  for (int k = 1; k < 16; k <<= 1){
    #pragma unroll
    for (int s = 0; s < 8; ++s){
      const float om1 = __shfl_xor(m1[s], k);
      const float om2 = __shfl_xor(m2[s], k);
      const int   oj  = __shfl_xor(j1[s], k);
      m2[s] = fminf(fminf(m2[s], om2), fmaxf(m1[s], om1));
      const bool tk = (om1 < m1[s]) || (om1 == m1[s] && oj < j1[s]);
      m1[s] = tk ? om1 : m1[s];
      j1[s] = tk ? oj  : j1[s];
    }
  }

  // ---- cross-wave merge: upper code-half -> LDS, lower merges ----
  if (wid >= 4 && lc == 0){
    #pragma unroll
    for (int s = 0; s < 8; ++s){
      mgm1[wid-4][gq][s] = m1[s];
      mgm2[wid-4][gq][s] = m2[s];
      mgj [wid-4][gq][s] = j1[s];
    }
  }
  __syncthreads();
  if (wid < 4){
    #pragma unroll
    for (int s = 0; s < 8; ++s){
      const float om1 = mgm1[wid][gq][s];
      const float om2 = mgm2[wid][gq][s];
      const int   oj  = mgj [wid][gq][s];
      m2[s] = fminf(fminf(m2[s], om2), fmaxf(m1[s], om1));
      const bool tk = om1 < m1[s];       // tie keeps lower half (smaller j)
      m1[s] = tk ? om1 : m1[s];
      j1[s] = tk ? oj  : j1[s];
    }

    // ---- finalize: cert test, idx write, loss, uncertain list ----
    const float cmax = fmaxf(fmaxf(cmaxp[0], cmaxp[1]),
                             fmaxf(cmaxp[2], cmaxp[3]));
    float lossw = 0.f;
    #pragma unroll
    for (int f = 0; f < 2; ++f){
      #pragma unroll
      for (int r = 0; r < 4; ++r){
        const int s = f*4 + r;
        const int vrow = (gq << 2) + r;
        const float znv = __shfl(f == 0 ? zn0 : zn1, vrow);
        if (lc == 0){
          const int p  = pb + f*16 + vrow;
          const int gi = (b_base + bl)*8192 + wbase + p*wstep;
          idxout[gi] = j1[s];                    // provisional if uncertain
          const float eb = fmaf(2.0e-6f, znv, 3.0e-4f * sqrtf(znv) * cmax);
          if (m2[s] - m1[s] > eb){
            lossw += znv + m1[s];
          } else {
            const int pos = atomicAdd(cnt, 1);
            if (pos < 131072) list[pos] = (((bl << 5) | g) << 8) | p;
          }
        }
      }
    }
    lossw += __shfl_xor(lossw, 16);
    lossw += __shfl_xor(lossw, 32);
    if (lane == 0) red[wid] = lossw;
  }
  __syncthreads();
  if (tid == 0) atomicAdd(lossacc, red[0] + red[1] + red[2] + red[3]);
}

// ---------------- np-bit-exact f32 fallback for uncertain vectors ----------
template<int LEVELS>
__global__ __launch_bounds__(256) void fb_rw(
    const float* __restrict__ z, const float* __restrict__ cb32,
    const float* __restrict__ cbn, const int* __restrict__ cnt,
    const int* __restrict__ list, int* __restrict__ idxout,
    float* __restrict__ lossacc, int b_base)
{
  const int lane = threadIdx.x & 63;
  const int wv = (blockIdx.x << 2) | (threadIdx.x >> 6);
  const int nw = gridDim.x << 2;
  int n = cnt[0];
  if (n > 131072) n = 131072;
  for (int it = wv; it < n; it += nw){
    const int id = list[it];
    const int p = id & 255, g = (id >> 8) & 31, bl = id >> 13;
    int cb, w;
    if (LEVELS == 4){ cb = (g & 3)*8 + (g >> 2); w = (g >> 2)*1024 + (p << 2) + (g & 3); }
    else            { cb = g;                    w = (g << 8) + p; }
    const int zoff = (((bl << 10) + cb) << 8) + p;
    float myz = 0.f;
    if (lane < 32) myz = z[zoff + (lane << 13)];
    // broadcast z to all lanes (register array; compile-time indexed)
    float zb[32];
    #pragma unroll
    for (int e = 0; e < 32; ++e) zb[e] = __shfl(myz, e);
    // zn: sequential ascending fmaf (matches np's accumulation order)
    float zn = 0.f;
    #pragma unroll
    for (int e = 0; e < 32; ++e) zn = fmaf(zb[e], zb[e], zn);
    float bd = __builtin_inff(); int bj = 0;
    #pragma unroll 4
    for (int jj = 0; jj < 16; ++jj){
      const int j = (jj << 6) + lane;
      const float4* c4 = reinterpret_cast<const float4*>(cb32 + (j << 5));
      float dot = 0.f;
      #pragma unroll
      for (int e4 = 0; e4 < 8; ++e4){
        const float4 cv = c4[e4];
        dot = fmaf(zb[(e4 << 2) + 0], cv.x, dot);
        dot = fmaf(zb[(e4 << 2) + 1], cv.y, dot);
        dot = fmaf(zb[(e4 << 2) + 2], cv.z, dot);
        dot = fmaf(zb[(e4 << 2) + 3], cv.w, dot);
      }
      const float d = (zn - 2.f*dot) + cbn[j];   // np's exact formula/rounding
      if (d < bd){ bd = d; bj = j; }
    }
    #pragma unroll
    for (int k = 1; k < 64; k <<= 1){
      const float od = __shfl_xor(bd, k);
      const int   oj = __shfl_xor(bj, k);
      if (od < bd || (od == bd && oj < bj)){ bd = od; bj = oj; }
    }
    if (lane == 0){
      idxout[(b_base + bl)*8192 + w] = bj;
      atomicAdd(lossacc, bd);                    // bd == |z-c|^2 (includes zn)
    }
  }
}

// -------- zqz: merged zq_p output + hcat-accum zero (independent work) -----
__global__ __launch_bounds__(256) void zqz_rw(const int* __restrict__ idxp,
    const float* __restrict__ cb32, float* __restrict__ out,
    float* __restrict__ acc0){
  const int bid = blockIdx.x;
  if (bid < 16384){
    int t = bid * 256 + threadIdx.x;
    int l = t & 3, n = (t >> 2) & 2047, e = (t >> 13) & 31, b = t >> 18;
    int id = idxp[b*8192 + (n << 2) + l];
    out[t] = cb32[((id & 1023) << 5) + e];
  } else {
    acc0[(bid - 16384) * 256 + threadIdx.x] = 0.f;
  }
}

extern "C" void kernel_launch(void* const* d_in, const int* in_sizes, int n_in,
                              void* d_out, int out_size, void* d_ws, size_t ws_size,
                              hipStream_t stream){
  (void)in_sizes; (void)n_in; (void)out_size;
  const void* x   = d_in[0];
  const void* ciw = d_in[1];
  const void* cib = d_in[2];
  const void* lwp = d_in[3];
  const void* lbp = d_in[4];
  const void* wpi = d_in[5];
  const void* bpi = d_in[6];
  const void* wpo = d_in[7];
  const void* bpo = d_in[8];
  const void* lwn = d_in[9];
  const void* lbn = d_in[10];
  const void* wni = d_in[11];
  const void* bni = d_in[12];
  const void* wno = d_in[13];
  const void* bno = d_in[14];
  const void* cbk = d_in[15];
  const void* cow = d_in[16];
  const void* cob = d_in[17];

  float* ws    = (float*)d_ws;
  float* flags = ws + FLAGS_OFF;
  float* loss  = ws + LOSS_OFF;
  float* stats = ws + STATS_OFF;
  float* cmaxp = ws + CMAX_OFF;
  float* cb32  = ws + CB32_OFF;
  float* cbn   = ws + CBN_OFF;
  int*   cnts  = (int*)(ws + CNT_OFF);
  int*   idxp  = (int*)(ws + IDXP_OFF);
  int*   idxn  = (int*)(ws + IDXN_OFF);
  short* cbhl  = (short*)(ws + CBHL_OFF);
  int*   list  = (int*)(ws + LIST_OFF);
  float* R2    = ws + R2_OFF;
  float* R3    = ws + R3_OFF;
  float* R1    = ws + R1_OFF;

  float* outO = (float*)d_out;
  float* outL = outO + 1048576;
  float* outZ = outO + 1048577;

  const size_t wsf = ws_size / 4;
  int CS = 4;
  if      (wsf >= (size_t)R1_OFF + 16u*262144u) CS = 16;
  else if (wsf >= (size_t)R1_OFF +  8u*262144u) CS = 8;

  // fused detect + codebook prep + accumulator init
  cbprep_rw<<<4, 256, 0, stream>>>(cbk, cb32, cbn, cbhl, ws);
  // h = conv_in(silu(x)) -> R1
  gemm2_rw<256,2,false,false,0><<<dim3(128,4), 256, 0, stream>>>(
      nullptr, nullptr, x, ciw, cib, nullptr, nullptr, nullptr, nullptr,
      R1, flags, 256, 256, 0, 0, 0, 0);
  stats_rw<<<32, 256, 0, stream>>>(R1, stats);
  ln_rw<<<4096, 256, 0, stream>>>(R1, lwp, lbp, lwn, lbn, stats, flags, R2, R3);
  // phylo: z chunks (R2 -> R1), MFMA quantize + np-exact fallback
  {
    int ci = 0;
    for (int c = 0; c < 16; c += CS, ++ci){
      gemm2_rw<128,0,true,false,0><<<dim3(CS*8,16), 256, 0, stream>>>(
          R2, nullptr, nullptr, wpi, bpi, nullptr, nullptr, nullptr, nullptr,
          R1, flags, 128, 1024, 0, c, 0, c);
      quantm_rw<4><<<CS*64, 512, 0, stream>>>(R1, cbhl, cbn, cmaxp,
                                              idxp, loss + 0, cnts + ci, list, c);
      fb_rw<4><<<640, 256, 0, stream>>>(R1, cb32, cbn, cnts + ci, list,
                                        idxp, loss + 0, c);
    }
  }
  // non-phylo
  {
    int ci = 4;
    for (int c = 0; c < 16; c += CS, ++ci){
      gemm2_rw<128,0,true,false,0><<<dim3(CS*8,16), 256, 0, stream>>>(
          R3, nullptr, nullptr, wni, bni, nullptr, nullptr, nullptr, nullptr,
          R1, flags, 128, 1024, 0, c, 0, c);
      quantm_rw<1><<<CS*64, 512, 0, stream>>>(R1, cbhl, cbn, cmaxp,
                                              idxn, loss + 1, cnts + ci, list, c);
      fb_rw<1><<<640, 256, 0, stream>>>(R1, cb32, cbn, cnts + ci, list,
                                        idxn, loss + 1, c);
    }
  }
  // zq_p output + hcat accum zero (merged; R2/R3 contiguous 1048576 floats)
  zqz_rw<<<20480, 256, 0, stream>>>(idxp, cb32, outZ, R2);
  // hout_p + hout_n merged: vectorized gather + split-K x4 x 2 groups
  houtg_rw<<<dim3(128, 2, 8), 256, 0, stream>>>(
      idxp, idxn, wpo, wno, cb32, R2, R3, flags);
  // out = conv_out(silu(hcat + hout_bias)) + fused loss finalize
  coutf_rw<<<dim3(128, 4), 256, 0, stream>>>(
      R2, R3, cow, cob, bpo, bno, outO, flags, loss, outL);
}

// Round 16
// 517.028 us; speedup vs baseline: 11.0708x; 11.0708x over previous
//
#include <hip/hip_runtime.h>
#include <hip/hip_bf16.h>

// Round 28: recover from r27 spill + minimal houtg fix. r27: full qc x cc
// unroll -> 8 live Bs-staging bodies, VGPR 256, 7.2GB scratch FETCH,
// 5.2ms. Revert houtg to r26-exact BODY (73us proven, total 515.8) and
// fix only its measured defect: As row-stride 32 -> bank=(spx+j)%32 =
// 8-way write conflict (3.1M counted). Pad As to [32][36] (stride%32=4):
// bank=(4*sch+spx+j)%32 -> ~2-way (free); read side 16 banks x 4-lane
// broadcast = conflict-free. Same values, same FMA order — bit-identical;
// only LDS layout changes. Everything else byte-identical to r26 (515.8).
// Outputs (f32): out[1048576] | loss[1] | zq_p[4194304].

typedef float f32x4  __attribute__((ext_vector_type(4)));
typedef short bf16x8 __attribute__((ext_vector_type(8)));

__device__ __forceinline__ float silu_rw(float x){ return x / (1.f + expf(-x)); }
__device__ __forceinline__ float b2f_rw(__hip_bfloat16 v){ return __bfloat162float(v); }
__device__ __forceinline__ float ldv_rw(const void* p, int i, int f32m){
  if (f32m) return ((const float*)p)[i];
  return b2f_rw(((const __hip_bfloat16*)p)[i]);
}
__device__ __forceinline__ unsigned short f2bf_rw(float x){   // f32 -> bf16 RNE
  unsigned u = __float_as_uint(x);
  unsigned r = ((u >> 16) & 1u) + 0x7FFFu;
  return (unsigned short)((u + r) >> 16);
}
__device__ __forceinline__ float bf2f_rw(unsigned short h){
  return __uint_as_float(((unsigned)h) << 16);
}

// ---------------- workspace layout (float offsets) ----------------
#define FLAGS_OFF 0
#define LOSS_OFF  4
#define STATS_OFF 8
#define CNT_OFF   72         // 8 ints: fallback counters per chunk
#define CMAX_OFF  80         // cmaxp[0..3]: per-cbprep-block max |c|
#define CB32_OFF  128        // 1024x32 f32
#define CBN_OFF   32896      // 1024
#define IDXP_OFF  33984      // 131072 int
#define IDXN_OFF  165056     // 131072 int
#define CBHL_OFF  296192     // interleaved hi/lo bf16 table (32768 f32 slots)
#define LIST_OFF  328960     // 131072 int (uncertain list, reused per chunk)
#define R2_OFF    460032     // lnp -> hcat_p accum (524288)
#define R3_OFF    984320     // lnn -> hcat_n accum (524288)
#define R1_OFF    1508608    // h (1048576) / z chunks (CS*262144)

// ------ cbprep v3: fused dtype-detect + codebook prep + accumulator init ---
__global__ __launch_bounds__(256) void cbprep_rw(const void* cbv,
    float* cb32, float* cbn, short* cbhl, float* wsb){
  __shared__ int bad_s;
  __shared__ float mx[256];
  const int tid = threadIdx.x;
  if (tid == 0) bad_s = 0;
  __syncthreads();
  const unsigned short* u = (const unsigned short*)cbv;
  int local = 0;
  for (int i = tid; i < 32768; i += 256){
    unsigned e = (u[i] >> 7) & 0xFF;
    if (e >= 126) local = 1;
  }
  if (local) bad_s = 1;
  __syncthreads();
  const int f32m = bad_s;

  const int j = blockIdx.x * 256 + tid;          // grid 4 -> j in [0,1024)
  float s = 0.f;
  const int tb = ((j >> 4) << 10) + ((j & 15) << 5);
  for (int e = 0; e < 32; ++e){
    float v = ldv_rw(cbv, j*32 + e, f32m);
    cb32[j*32 + e] = v;
    unsigned short h = f2bf_rw(v);
    cbhl[tb + e]       = (short)h;
    cbhl[tb + e + 512] = (short)f2bf_rw(v - bf2f_rw(h));
    s += v*v;
  }
  cbn[j] = s;
  mx[tid] = sqrtf(s);
  __syncthreads();
  for (int st = 128; st > 0; st >>= 1){
    if (tid < st) mx[tid] = fmaxf(mx[tid], mx[tid + st]);
    __syncthreads();
  }
  if (tid == 0){
    wsb[CMAX_OFF + blockIdx.x] = mx[0];
    wsb[FLAGS_OFF] = f32m ? 1.f : 0.f;           // idempotent across blocks
    if (blockIdx.x == 0){
      wsb[LOSS_OFF] = 0.f; wsb[LOSS_OFF + 1] = 0.f;
      int* c = (int*)(wsb + CNT_OFF);
      #pragma unroll
      for (int k = 0; k < 8; ++k) c[k] = 0;
    }
  }
}

// ---------------- gemm2 (r11, verified): 32px x 64out tiles ----------------
// Instantiated here only for INMODE 0 (z-gemm) and 2 (conv_in).
template<int KCH, int INMODE, bool OUTSILU, bool ATOMIC, int LEVELS>
__global__ __launch_bounds__(256) void gemm2_rw(
    const float* __restrict__ inF, const float* __restrict__ inF2,
    const void* __restrict__ inV,
    const void* __restrict__ W, const void* __restrict__ biasO,
    const void* __restrict__ sbA, const void* __restrict__ sbB,
    const int* __restrict__ idxin, const float* __restrict__ cb32,
    float* __restrict__ outF, const float* __restrict__ flags,
    int KDIM, int OUTC, int o_off, int b_base, int ib_sub, int ob_sub)
{
  __shared__ float As[32][32];
  __shared__ float Bs[32][68];

  const int f32m = (flags[0] != 0.f);
  const int t  = threadIdx.x;
  const int q0 = (blockIdx.x << 5) + (b_base << 8);
  const int b  = q0 >> 8;
  const int p0 = q0 & 255;
  const int o0 = blockIdx.y << 6;
  const int k0base = blockIdx.z * KCH;
  const int tx = t & 15, ty = t >> 4;
  float acc[4][2] = {};

  const int sch = t >> 3, spx = (t & 7) << 2;

  for (int kc = 0; kc < KCH; kc += 32){
    const int k0 = k0base + kc;
    if constexpr (INMODE == 0){
      const float4 v = *reinterpret_cast<const float4*>(
          &inF[(((b - ib_sub)*KDIM + k0 + sch) << 8) + p0 + spx]);
      *reinterpret_cast<float4*>(&As[sch][spx]) = v;
    } else { // INMODE 2
      if (f32m){
        const float* xf = (const float*)inV;
        float4 v = *reinterpret_cast<const float4*>(&xf[((b*KDIM + k0 + sch) << 8) + p0 + spx]);
        v.x = silu_rw(v.x); v.y = silu_rw(v.y); v.z = silu_rw(v.z); v.w = silu_rw(v.w);
        *reinterpret_cast<float4*>(&As[sch][spx]) = v;
      } else {
        const __hip_bfloat16* xb = (const __hip_bfloat16*)inV;
        const int off = ((b*KDIM + k0 + sch) << 8) + p0 + spx;
        #pragma unroll
        for (int j = 0; j < 4; ++j) As[sch][spx + j] = silu_rw(b2f_rw(xb[off + j]));
      }
    }
    if (f32m){
      const float* Wf = (const float*)W;
      #pragma unroll
      for (int r = 0; r < 8; ++r){
        int ii = t + (r << 8); int oo = ii >> 5, cc = ii & 31;
        Bs[cc][oo] = Wf[(o0 + oo)*KDIM + k0 + cc];
      }
    } else {
      const __hip_bfloat16* Wb = (const __hip_bfloat16*)W;
      #pragma unroll
      for (int r = 0; r < 8; ++r){
        int ii = t + (r << 8); int oo = ii >> 5, cc = ii & 31;
        Bs[cc][oo] = b2f_rw(Wb[(o0 + oo)*KDIM + k0 + cc]);
      }
    }
    __syncthreads();
    #pragma unroll
    for (int kk = 0; kk < 32; ++kk){
      const float2 a = *reinterpret_cast<const float2*>(&As[kk][tx << 1]);
      const float4 w = *reinterpret_cast<const float4*>(&Bs[kk][ty << 2]);
      acc[0][0] += w.x*a.x; acc[0][1] += w.x*a.y;
      acc[1][0] += w.y*a.x; acc[1][1] += w.y*a.y;
      acc[2][0] += w.z*a.x; acc[2][1] += w.z*a.y;
      acc[3][0] += w.w*a.x; acc[3][1] += w.w*a.y;
    }
    __syncthreads();
  }
  #pragma unroll
  for (int i = 0; i < 4; ++i){
    const int o = o0 + (ty << 2) + i;
    const int base = (((b - ob_sub)*OUTC + o_off + o) << 8) + p0 + (tx << 1);
    const float bb = ldv_rw(biasO, o, f32m);
    float v0 = acc[i][0] + bb, v1 = acc[i][1] + bb;
    if constexpr (OUTSILU){ v0 = silu_rw(v0); v1 = silu_rw(v1); }
    *reinterpret_cast<float2*>(&outF[base]) = make_float2(v0, v1);
  }
}

// ------- houtg v3: r26-exact body, As padded [32][36] (conflict fix) -------
// Grid (128, 2, 8): z>>2 selects group (0=p LEVELS4, 1=n LEVELS1), z&3 is
// the split-K slice (k0 = kz*256 of KDIM 1024). Identical values and FMA
// order to r26; only As row stride changed 32->36 so the scalar writes
// As[sch][spx+j] hit bank (4*sch+spx+j)%32 (~2-way, free) instead of
// (spx+j)%32 (8-way, 3.1M counted conflicts).
__global__ __launch_bounds__(256) void houtg_rw(
    const int* __restrict__ idxp, const int* __restrict__ idxn,
    const void* __restrict__ Wp, const void* __restrict__ Wn,
    const float* __restrict__ cb32, float* __restrict__ R2,
    float* __restrict__ R3, const float* __restrict__ flags)
{
  __shared__ float As[32][36];
  __shared__ float Bs[32][68];
  __shared__ int   IdxS[32][32];

  const int f32m = (flags[0] != 0.f);
  const int grp = blockIdx.z >> 2;
  const int* __restrict__ idxin = grp ? idxn : idxp;
  const void* __restrict__ W    = grp ? Wn : Wp;
  float* __restrict__ outF      = grp ? R3 : R2;

  const int t  = threadIdx.x;
  const int q0 = blockIdx.x << 5;
  const int b  = q0 >> 8;
  const int p0 = q0 & 255;
  const int o0 = blockIdx.y << 6;
  const int k0base = (blockIdx.z & 3) * 256;
  const int tx = t & 15, ty = t >> 4;
  float acc[4][2] = {};

  const int sch = t >> 3, spx = (t & 7) << 2;

  #pragma unroll
  for (int j = 0; j < 4; ++j){
    const int p = p0 + spx + j;
    if (grp == 0){                      // LEVELS 4 (phylo)
      const int l = sch >> 3, kp = sch & 7;
      IdxS[sch][spx + j] = idxin[b*8192 + (((kp << 8) + p) << 2) + l];
    } else {                            // LEVELS 1
      IdxS[sch][spx + j] = idxin[b*8192 + (sch << 8) + p];
    }
  }
  __syncthreads();

  for (int kc = 0; kc < 256; kc += 32){
    const int k0 = k0base + kc;
    const int e = k0 >> 5;
    #pragma unroll
    for (int j = 0; j < 4; ++j)
      As[sch][spx + j] = cb32[((IdxS[sch][spx + j] & 1023) << 5) + e];
    if (f32m){
      const float* Wf = (const float*)W;
      #pragma unroll
      for (int r = 0; r < 8; ++r){
        int ii = t + (r << 8); int oo = ii >> 5, cc = ii & 31;
        Bs[cc][oo] = Wf[(o0 + oo)*1024 + k0 + cc];
      }
    } else {
      const __hip_bfloat16* Wb = (const __hip_bfloat16*)W;
      #pragma unroll
      for (int r = 0; r < 8; ++r){
        int ii = t + (r << 8); int oo = ii >> 5, cc = ii & 31;
        Bs[cc][oo] = b2f_rw(Wb[(o0 + oo)*1024 + k0 + cc]);
      }
    }
    __syncthreads();
    #pragma unroll
    for (int kk = 0; kk < 32; ++kk){
      const float2 a = *reinterpret_cast<const float2*>(&As[kk][tx << 1]);
      const float4 w = *reinterpret_cast<const float4*>(&Bs[kk][ty << 2]);
      acc[0][0] += w.x*a.x; acc[0][1] += w.x*a.y;
      acc[1][0] += w.y*a.x; acc[1][1] += w.y*a.y;
      acc[2][0] += w.z*a.x; acc[2][1] += w.z*a.y;
      acc[3][0] += w.w*a.x; acc[3][1] += w.w*a.y;
    }
    __syncthreads();
  }
  #pragma unroll
  for (int i = 0; i < 4; ++i){
    const int o = o0 + (ty << 2) + i;
    const int base = ((b*128 + o) << 8) + p0 + (tx << 1);
    atomicAdd(&outF[base + 0], acc[i][0]);
    atomicAdd(&outF[base + 1], acc[i][1]);
  }
}

// ------- coutf: conv_out (r18 INMODE5 semantics) + fused loss finalize -----
__global__ __launch_bounds__(256) void coutf_rw(
    const float* __restrict__ inF, const float* __restrict__ inF2,
    const void* __restrict__ W, const void* __restrict__ biasO,
    const void* __restrict__ sbA, const void* __restrict__ sbB,
    float* __restrict__ outF, const float* __restrict__ flags,
    const float* __restrict__ lossacc, float* __restrict__ outL)
{
  __shared__ float As[32][32];
  __shared__ float Bs[32][68];

  const int f32m = (flags[0] != 0.f);
  const int t  = threadIdx.x;
  const int q0 = blockIdx.x << 5;
  const int b  = q0 >> 8;
  const int p0 = q0 & 255;
  const int o0 = blockIdx.y << 6;
  const int tx = t & 15, ty = t >> 4;
  float acc[4][2] = {};

  const int sch = t >> 3, spx = (t & 7) << 2;

  if (blockIdx.x == 0 && blockIdx.y == 0 && t == 0)
    outL[0] = 1.25f * (lossacc[0] + lossacc[1]) * (1.f/4194304.f);

  for (int kc = 0; kc < 256; kc += 32){
    const int k0 = kc;
    const float* src = (k0 < 128) ? inF : inF2;
    const void* sb   = (k0 < 128) ? sbA : sbB;
    const int kh = k0 & 127;
    const float bb = ldv_rw(sb, kh + sch, f32m);
    float4 v = *reinterpret_cast<const float4*>(&src[((b*128 + kh + sch) << 8) + p0 + spx]);
    v.x = silu_rw(v.x + bb); v.y = silu_rw(v.y + bb);
    v.z = silu_rw(v.z + bb); v.w = silu_rw(v.w + bb);
    *reinterpret_cast<float4*>(&As[sch][spx]) = v;
    if (f32m){
      const float* Wf = (const float*)W;
      #pragma unroll
      for (int r = 0; r < 8; ++r){
        int ii = t + (r << 8); int oo = ii >> 5, cc = ii & 31;
        Bs[cc][oo] = Wf[(o0 + oo)*256 + k0 + cc];
      }
    } else {
      const __hip_bfloat16* Wb = (const __hip_bfloat16*)W;
      #pragma unroll
      for (int r = 0; r < 8; ++r){
        int ii = t + (r << 8); int oo = ii >> 5, cc = ii & 31;
        Bs[cc][oo] = b2f_rw(Wb[(o0 + oo)*256 + k0 + cc]);
      }
    }
    __syncthreads();
    #pragma unroll
    for (int kk = 0; kk < 32; ++kk){
      const float2 a = *reinterpret_cast<const float2*>(&As[kk][tx << 1]);
      const float4 w = *reinterpret_cast<const float4*>(&Bs[kk][ty << 2]);
      acc[0][0] += w.x*a.x; acc[0][1] += w.x*a.y;
      acc[1][0] += w.y*a.x; acc[1][1] += w.y*a.y;
      acc[2][0] += w.z*a.x; acc[2][1] += w.z*a.y;
      acc[3][0] += w.w*a.x; acc[3][1] += w.w*a.y;
    }
    __syncthreads();
  }
  #pragma unroll
  for (int i = 0; i < 4; ++i){
    const int o = o0 + (ty << 2) + i;
    const int base = ((b*256 + o) << 8) + p0 + (tx << 1);
    const float bb = ldv_rw(biasO, o, f32m);
    *reinterpret_cast<float2*>(&outF[base]) =
        make_float2(acc[i][0] + bb, acc[i][1] + bb);
  }
}

// ---------------- per-sample LN stats over silu(h_half) ----------------
__global__ __launch_bounds__(256) void stats_rw(const float* __restrict__ h, float* __restrict__ stats){
  const int b = blockIdx.x >> 1, half = blockIdx.x & 1;
  const float* base = h + ((b*256 + half*128) << 8);
  float s = 0.f, s2 = 0.f;
  for (int i = threadIdx.x; i < 32768; i += 256){
    float a = silu_rw(base[i]);
    s += a; s2 += a*a;
  }
  __shared__ float sh[2][256];
  sh[0][threadIdx.x] = s; sh[1][threadIdx.x] = s2;
  __syncthreads();
  for (int st = 128; st > 0; st >>= 1){
    if (threadIdx.x < st){
      sh[0][threadIdx.x] += sh[0][threadIdx.x + st];
      sh[1][threadIdx.x] += sh[1][threadIdx.x + st];
    }
    __syncthreads();
  }
  if (threadIdx.x == 0){
    float mu  = sh[0][0] * (1.f/32768.f);
    float var = sh[1][0] * (1.f/32768.f) - mu*mu;
    stats[half*32 + b]      = mu;
    stats[half*32 + 16 + b] = 1.f / sqrtf(var + 1e-5f);
  }
}

// ---------------- LN apply ----------------
__global__ __launch_bounds__(256) void ln_rw(const float* __restrict__ h,
    const void* lwp, const void* lbp, const void* lwn, const void* lbn,
    const float* __restrict__ stats, const float* __restrict__ flags,
    float* __restrict__ lnp, float* __restrict__ lnn){
  const int f32m = (flags[0] != 0.f);
  int i = blockIdx.x * 256 + threadIdx.x;
  int b = i >> 16, c = (i >> 8) & 255, p = i & 255;
  float a = silu_rw(h[i]);
  if (c < 128){
    float v = (a - stats[b]) * stats[16 + b] * ldv_rw(lwp, (c << 8) + p, f32m) + ldv_rw(lbp, (c << 8) + p, f32m);
    lnp[((b*128 + c) << 8) + p] = v;
  } else {
    int cc = c - 128;
    float v = (a - stats[32 + b]) * stats[48 + b] * ldv_rw(lwn, (cc << 8) + p, f32m) + ldv_rw(lbn, (cc << 8) + p, f32m);
    lnn[((b*128 + cc) << 8) + p] = v;
  }
}

// ---------------- VQ search v6b (r18-exact; cmax = max of 4 partials) ------
template<int LEVELS>
__global__ __launch_bounds__(512, 4) void quantm_rw(
    const float* __restrict__ z, const short* __restrict__ cbhl,
    const float* __restrict__ cbn, const float* __restrict__ cmaxp,
    int* __restrict__ idxout, float* __restrict__ lossacc,
    int* __restrict__ cnt, int* __restrict__ list, int b_base)
{
  __shared__ float mgm1[4][4][8], mgm2[4][4][8];
  __shared__ int   mgj [4][4][8];
  __shared__ float red[4];

  const int tid  = threadIdx.x;
  const int lane = tid & 63, wid = tid >> 6;
  const int lc = lane & 15, gq = lane >> 4;
  const int pg = wid & 3, ch = wid >> 2;    // pixel group, code half
  const int bid  = blockIdx.x;
  const int bl   = bid >> 6;                // local batch
  const int rest = bid & 63;
  const int g = rest >> 1, half = rest & 1;
  int cb, wbase, wstep;
  if (LEVELS == 4){ cb = (g & 3)*8 + (g >> 2); wbase = (g >> 2)*1024 + (g & 3); wstep = 4; }
  else            { cb = g;                    wbase = g << 8;                  wstep = 1; }
  const int pb = half*128 + pg*32;

  // ---- load z rows, build -2z hi/lo bf16 A-fragments, partial |z|^2 ----
  bf16x8 ah0, al0, ah1, al1;
  float zn0 = 0.f, zn1 = 0.f;
  const int zoff = (((bl << 10) + cb) << 8) + pb + lc;
  const int e0 = gq << 3;
  #pragma unroll
  for (int i = 0; i < 8; ++i){
    const int zo = zoff + ((e0 + i) << 13);
    const float z0 = z[zo];
    const float z1 = z[zo + 16];
    zn0 += z0*z0; zn1 += z1*z1;
    const float s0 = -2.f*z0, s1 = -2.f*z1;
    const unsigned short h0 = f2bf_rw(s0);
    const unsigned short h1 = f2bf_rw(s1);
    ah0[i] = (short)h0; al0[i] = (short)f2bf_rw(s0 - bf2f_rw(h0));
    ah1[i] = (short)h1; al1[i] = (short)f2bf_rw(s1 - bf2f_rw(h1));
  }
  zn0 += __shfl_xor(zn0, 16); zn0 += __shfl_xor(zn0, 32);   // full zn for row lc
  zn1 += __shfl_xor(zn1, 16); zn1 += __shfl_xor(zn1, 32);

  float m1[8], m2[8]; int j1[8];
  #pragma unroll
  for (int s = 0; s < 8; ++s){ m1[s] = __builtin_inff(); m2[s] = __builtin_inff(); j1[s] = 0; }

  // interleaved table: wave's tiles T = ch*32 + t; shorts base:
  const short* bp  = cbhl + (ch << 15) + (lc << 5) + (gq << 3);
  const float* cnp = cbn + (ch << 9) + lc;

  bf16x8 bh  = *reinterpret_cast<const bf16x8*>(bp);
  bf16x8 blo = *reinterpret_cast<const bf16x8*>(bp + 512);
  float  cnv = cnp[0];

  #pragma unroll 2
  for (int t = 0; t < 32; ++t){
    const int tn = (t < 31) ? t + 1 : 31;      // clamped prefetch index
    const bf16x8 bhn  = *reinterpret_cast<const bf16x8*>(bp + (tn << 10));
    const bf16x8 blon = *reinterpret_cast<const bf16x8*>(bp + (tn << 10) + 512);
    const float  cnn  = cnp[tn << 4];

    f32x4 a0 = {cnv, cnv, cnv, cnv};
    f32x4 a1 = {cnv, cnv, cnv, cnv};
    a0 = __builtin_amdgcn_mfma_f32_16x16x32_bf16(ah0, bh,  a0, 0, 0, 0);
    a0 = __builtin_amdgcn_mfma_f32_16x16x32_bf16(ah0, blo, a0, 0, 0, 0);
    a0 = __builtin_amdgcn_mfma_f32_16x16x32_bf16(al0, bh,  a0, 0, 0, 0);
    a1 = __builtin_amdgcn_mfma_f32_16x16x32_bf16(ah1, bh,  a1, 0, 0, 0);
    a1 = __builtin_amdgcn_mfma_f32_16x16x32_bf16(ah1, blo, a1, 0, 0, 0);
    a1 = __builtin_amdgcn_mfma_f32_16x16x32_bf16(al1, bh,  a1, 0, 0, 0);

    const int jc = (((ch << 5) + t) << 4) + lc;
    #pragma unroll
    for (int r = 0; r < 4; ++r){
      const float d0 = a0[r];
      m2[r] = __builtin_amdgcn_fmed3f(d0, m1[r], m2[r]);
      const bool t0 = d0 < m1[r];
      j1[r] = t0 ? jc : j1[r]; m1[r] = t0 ? d0 : m1[r];
      const float d1 = a1[r];
      m2[4+r] = __builtin_amdgcn_fmed3f(d1, m1[4+r], m2[4+r]);
      const bool t1 = d1 < m1[4+r];
      j1[4+r] = t1 ? jc : j1[4+r]; m1[4+r] = t1 ? d1 : m1[4+r];
    }
    bh = bhn; blo = blon; cnv = cnn;
  }

  // ---- 16-lane top-2 merge (cols of each row live in one 16-lane group) ----
  #pragma unroll
  for (int k = 1; k < 16; k <<= 1){
    #pragma unroll
    for (int s = 0; s < 8; ++s){
      const float om1 = __shfl_xor(m1[s], k);
      const float om2 = __shfl_xor(m2[s], k);
      const int   oj  = __shfl_xor(j1[s], k);
      m2[s] = fminf(fminf(m2[s], om2), fmaxf(m1[s], om1));
      const bool tk = (om1 < m1[s]) || (om1 == m1[s] && oj < j1[s]);
      m1[s] = tk ? om1 : m1[s];
      j1[s] = tk ? oj  : j1[s];
    }
  }

  // ---- cross-wave merge: upper code-half -> LDS, lower merges ----
  if (wid >= 4 && lc == 0){
    #pragma unroll
    for (int s = 0; s < 8; ++s){
      mgm1[wid-4][gq][s] = m1[s];
      mgm2[wid-4][gq][s] = m2[s];
      mgj [wid-4][gq][s] = j1[s];
    }
  }
  __syncthreads();
  if (wid < 4){
    #pragma unroll
    for (int s = 0; s < 8; ++s){
      const float om1 = mgm1[wid][gq][s];
      const float om2 = mgm2[wid][gq][s];
      const int   oj  = mgj [wid][gq][s];
      m2[s] = fminf(fminf(m2[s], om2), fmaxf(m1[s], om1));
      const bool tk = om1 < m1[s];       // tie keeps lower half (smaller j)
      m1[s] = tk ? om1 : m1[s];
      j1[s] = tk ? oj  : j1[s];
    }

    // ---- finalize: cert test, idx write, loss, uncertain list ----
    const float cmax = fmaxf(fmaxf(cmaxp[0], cmaxp[1]),
                             fmaxf(cmaxp[2], cmaxp[3]));
    float lossw = 0.f;
    #pragma unroll
    for (int f = 0; f < 2; ++f){
      #pragma unroll
      for (int r = 0; r < 4; ++r){
        const int s = f*4 + r;
        const int vrow = (gq << 2) + r;
        const float znv = __shfl(f == 0 ? zn0 : zn1, vrow);
        if (lc == 0){
          const int p  = pb + f*16 + vrow;
          const int gi = (b_base + bl)*8192 + wbase + p*wstep;
          idxout[gi] = j1[s];                    // provisional if uncertain
          const float eb = fmaf(2.0e-6f, znv, 3.0e-4f * sqrtf(znv) * cmax);
          if (m2[s] - m1[s] > eb){
            lossw += znv + m1[s];
          } else {
            const int pos = atomicAdd(cnt, 1);
            if (pos < 131072) list[pos] = (((bl << 5) | g) << 8) | p;
          }
        }
      }
    }
    lossw += __shfl_xor(lossw, 16);
    lossw += __shfl_xor(lossw, 32);
    if (lane == 0) red[wid] = lossw;
  }
  __syncthreads();
  if (tid == 0) atomicAdd(lossacc, red[0] + red[1] + red[2] + red[3]);
}

// ---------------- np-bit-exact f32 fallback for uncertain vectors ----------
template<int LEVELS>
__global__ __launch_bounds__(256) void fb_rw(
    const float* __restrict__ z, const float* __restrict__ cb32,
    const float* __restrict__ cbn, const int* __restrict__ cnt,
    const int* __restrict__ list, int* __restrict__ idxout,
    float* __restrict__ lossacc, int b_base)
{
  const int lane = threadIdx.x & 63;
  const int wv = (blockIdx.x << 2) | (threadIdx.x >> 6);
  const int nw = gridDim.x << 2;
  int n = cnt[0];
  if (n > 131072) n = 131072;
  for (int it = wv; it < n; it += nw){
    const int id = list[it];
    const int p = id & 255, g = (id >> 8) & 31, bl = id >> 13;
    int cb, w;
    if (LEVELS == 4){ cb = (g & 3)*8 + (g >> 2); w = (g >> 2)*1024 + (p << 2) + (g & 3); }
    else            { cb = g;                    w = (g << 8) + p; }
    const int zoff = (((bl << 10) + cb) << 8) + p;
    float myz = 0.f;
    if (lane < 32) myz = z[zoff + (lane << 13)];
    // broadcast z to all lanes (register array; compile-time indexed)
    float zb[32];
    #pragma unroll
    for (int e = 0; e < 32; ++e) zb[e] = __shfl(myz, e);
    // zn: sequential ascending fmaf (matches np's accumulation order)
    float zn = 0.f;
    #pragma unroll
    for (int e = 0; e < 32; ++e) zn = fmaf(zb[e], zb[e], zn);
    float bd = __builtin_inff(); int bj = 0;
    #pragma unroll 4
    for (int jj = 0; jj < 16; ++jj){
      const int j = (jj << 6) + lane;
      const float4* c4 = reinterpret_cast<const float4*>(cb32 + (j << 5));
      float dot = 0.f;
      #pragma unroll
      for (int e4 = 0; e4 < 8; ++e4){
        const float4 cv = c4[e4];
        dot = fmaf(zb[(e4 << 2) + 0], cv.x, dot);
        dot = fmaf(zb[(e4 << 2) + 1], cv.y, dot);
        dot = fmaf(zb[(e4 << 2) + 2], cv.z, dot);
        dot = fmaf(zb[(e4 << 2) + 3], cv.w, dot);
      }
      const float d = (zn - 2.f*dot) + cbn[j];   // np's exact formula/rounding
      if (d < bd){ bd = d; bj = j; }
    }
    #pragma unroll
    for (int k = 1; k < 64; k <<= 1){
      const float od = __shfl_xor(bd, k);
      const int   oj = __shfl_xor(bj, k);
      if (od < bd || (od == bd && oj < bj)){ bd = od; bj = oj; }
    }
    if (lane == 0){
      idxout[(b_base + bl)*8192 + w] = bj;
      atomicAdd(lossacc, bd);                    // bd == |z-c|^2 (includes zn)
    }
  }
}

// -------- zqz: merged zq_p output + hcat-accum zero (independent work) -----
__global__ __launch_bounds__(256) void zqz_rw(const int* __restrict__ idxp,
    const float* __restrict__ cb32, float* __restrict__ out,
    float* __restrict__ acc0){
  const int bid = blockIdx.x;
  if (bid < 16384){
    int t = bid * 256 + threadIdx.x;
    int l = t & 3, n = (t >> 2) & 2047, e = (t >> 13) & 31, b = t >> 18;
    int id = idxp[b*8192 + (n << 2) + l];
    out[t] = cb32[((id & 1023) << 5) + e];
  } else {
    acc0[(bid - 16384) * 256 + threadIdx.x] = 0.f;
  }
}

extern "C" void kernel_launch(void* const* d_in, const int* in_sizes, int n_in,
                              void* d_out, int out_size, void* d_ws, size_t ws_size,
                              hipStream_t stream){
  (void)in_sizes; (void)n_in; (void)out_size;
  const void* x   = d_in[0];
  const void* ciw = d_in[1];
  const void* cib = d_in[2];
  const void* lwp = d_in[3];
  const void* lbp = d_in[4];
  const void* wpi = d_in[5];
  const void* bpi = d_in[6];
  const void* wpo = d_in[7];
  const void* bpo = d_in[8];
  const void* lwn = d_in[9];
  const void* lbn = d_in[10];
  const void* wni = d_in[11];
  const void* bni = d_in[12];
  const void* wno = d_in[13];
  const void* bno = d_in[14];
  const void* cbk = d_in[15];
  const void* cow = d_in[16];
  const void* cob = d_in[17];

  float* ws    = (float*)d_ws;
  float* flags = ws + FLAGS_OFF;
  float* loss  = ws + LOSS_OFF;
  float* stats = ws + STATS_OFF;
  float* cmaxp = ws + CMAX_OFF;
  float* cb32  = ws + CB32_OFF;
  float* cbn   = ws + CBN_OFF;
  int*   cnts  = (int*)(ws + CNT_OFF);
  int*   idxp  = (int*)(ws + IDXP_OFF);
  int*   idxn  = (int*)(ws + IDXN_OFF);
  short* cbhl  = (short*)(ws + CBHL_OFF);
  int*   list  = (int*)(ws + LIST_OFF);
  float* R2    = ws + R2_OFF;
  float* R3    = ws + R3_OFF;
  float* R1    = ws + R1_OFF;

  float* outO = (float*)d_out;
  float* outL = outO + 1048576;
  float* outZ = outO + 1048577;

  const size_t wsf = ws_size / 4;
  int CS = 4;
  if      (wsf >= (size_t)R1_OFF + 16u*262144u) CS = 16;
  else if (wsf >= (size_t)R1_OFF +  8u*262144u) CS = 8;

  // fused detect + codebook prep + accumulator init
  cbprep_rw<<<4, 256, 0, stream>>>(cbk, cb32, cbn, cbhl, ws);
  // h = conv_in(silu(x)) -> R1
  gemm2_rw<256,2,false,false,0><<<dim3(128,4), 256, 0, stream>>>(
      nullptr, nullptr, x, ciw, cib, nullptr, nullptr, nullptr, nullptr,
      R1, flags, 256, 256, 0, 0, 0, 0);
  stats_rw<<<32, 256, 0, stream>>>(R1, stats);
  ln_rw<<<4096, 256, 0, stream>>>(R1, lwp, lbp, lwn, lbn, stats, flags, R2, R3);
  // phylo: z chunks (R2 -> R1), MFMA quantize + np-exact fallback
  {
    int ci = 0;
    for (int c = 0; c < 16; c += CS, ++ci){
      gemm2_rw<128,0,true,false,0><<<dim3(CS*8,16), 256, 0, stream>>>(
          R2, nullptr, nullptr, wpi, bpi, nullptr, nullptr, nullptr, nullptr,
          R1, flags, 128, 1024, 0, c, 0, c);
      quantm_rw<4><<<CS*64, 512, 0, stream>>>(R1, cbhl, cbn, cmaxp,
                                              idxp, loss + 0, cnts + ci, list, c);
      fb_rw<4><<<640, 256, 0, stream>>>(R1, cb32, cbn, cnts + ci, list,
                                        idxp, loss + 0, c);
    }
  }
  // non-phylo
  {
    int ci = 4;
    for (int c = 0; c < 16; c += CS, ++ci){
      gemm2_rw<128,0,true,false,0><<<dim3(CS*8,16), 256, 0, stream>>>(
          R3, nullptr, nullptr, wni, bni, nullptr, nullptr, nullptr, nullptr,
          R1, flags, 128, 1024, 0, c, 0, c);
      quantm_rw<1><<<CS*64, 512, 0, stream>>>(R1, cbhl, cbn, cmaxp,
                                              idxn, loss + 1, cnts + ci, list, c);
      fb_rw<1><<<640, 256, 0, stream>>>(R1, cb32, cbn, cnts + ci, list,
                                        idxn, loss + 1, c);
    }
  }
  // zq_p output + hcat accum zero (merged; R2/R3 contiguous 1048576 floats)
  zqz_rw<<<20480, 256, 0, stream>>>(idxp, cb32, outZ, R2);
  // hout_p + hout_n merged: fused gather + split-K x4 x 2 groups, atomic
  houtg_rw<<<dim3(128, 2, 8), 256, 0, stream>>>(
      idxp, idxn, wpo, wno, cb32, R2, R3, flags);
  // out = conv_out(silu(hcat + hout_bias)) + fused loss finalize
  coutf_rw<<<dim3(128, 4), 256, 0, stream>>>(
      R2, R3, cow, cob, bpo, bno, outO, flags, loss, outL);
}